// Round 1
// baseline (123.519 us; speedup 1.0000x reference)
//
#include <hip/hip_runtime.h>
#include <math.h>

#define NCODES 16
#define NHALF 8
#define LOG2E 1.4426950408889634f

// f(xn) lookup table: TABN entries over xn in [0, TABMAX), linear interp.
// f is Gaussian-smoothed (sigma = sqrt(T/2) ~ 0.5) code lattice => smooth,
// |f''| <= ~2  =>  interp err <= 2*(1/64)^2/8 ~ 6e-5  (vs 7.8e-3 tolerance).
#define TABN 1024
#define TABMAX 16.0f
#define TABSCALE ((float)TABN / TABMAX)   /* 64.0f */

typedef float f32x4 __attribute__((ext_vector_type(4)));

// ThermoQuantizer: per-128-group abs-mean scale, soft-quantize to uniform
// 16-level codebook via softmax over -(x_norm-c)^2/T, lerp with pressure.
//
// v2: the exact even/odd Horner softmax-collapse (~40 VALU/elem) was nearly
// VALU-bound against the HBM roofline (24 vs 20.5 B/cyc/CU). Replace the
// per-element evaluation with a per-block LDS table of f(xn)=qx_norm(|x_n|)
// built ONCE with the exact Horner (1025 nodes, 4 evals/thread), then the
// main loop is ~12 VALU + one 8B LDS gather per element -> memory-bound.
__global__ __launch_bounds__(256) void tq_kernel(
    const float* __restrict__ x,
    const float* __restrict__ cb,
    const float* __restrict__ pp,
    const float* __restrict__ tp,
    float* __restrict__ out,
    int n4)
{
    const float pressure = pp[0];
    const float invT = 1.0f / (tp[0] + 1e-6f);

    __shared__ float tab[TABN + 1];   // +1 so interp at idx=TABN-1 is valid

    // ---- Build table: exact algebraic collapse, as in v1 ----
    // prob_i ∝ exp((2 x c_i - c_i^2)/T); for x>=0 with codes descending from
    // +1: term_j = W_j q^j, W_j = exp(-C_j^2/T), q = exp(-2|xn|*step/T).
    // Even/odd Horner split in q2 -> 4 independent 7-fma chains per node.
    {
        float WE[NHALF], WO[NHALF], WCE[NHALF], WCO[NHALF];
#pragma unroll
        for (int h = 0; h < NHALF; ++h) {
            float ce = cb[NCODES - 1 - 2 * h];        // j = 2h
            float co = cb[NCODES - 2 - 2 * h];        // j = 2h+1
            float we = exp2f(-ce * ce * invT * LOG2E);
            float wo = exp2f(-co * co * invT * LOG2E);
            WE[h] = we;  WCE[h] = we * ce;
            WO[h] = wo;  WCO[h] = wo * co;
        }
        const float step = (cb[NCODES - 1] - cb[0]) * (1.0f / 15.0f);
        const float kq = 2.0f * step * invT * LOG2E;  // q = exp2(-xn * kq)

        for (int t = threadIdx.x; t <= TABN; t += 256) {
            float xn = (float)t * (1.0f / TABSCALE);
            float q  = exp2f(-xn * kq);
            float q2 = q * q;
            float en = WCE[NHALF - 1], on = WCO[NHALF - 1];
            float ed = WE[NHALF - 1],  od = WO[NHALF - 1];
#pragma unroll
            for (int h = NHALF - 2; h >= 0; --h) {
                en = fmaf(en, q2, WCE[h]);
                on = fmaf(on, q2, WCO[h]);
                ed = fmaf(ed, q2, WE[h]);
                od = fmaf(od, q2, WO[h]);
            }
            float num = fmaf(q, on, en);
            float den = fmaf(q, od, ed);
            tab[t] = num * __builtin_amdgcn_rcpf(den);
        }
    }
    __syncthreads();

    const int stride = gridDim.x * blockDim.x;
    for (int i = blockIdx.x * blockDim.x + threadIdx.x; i < n4; i += stride) {
        f32x4 v = __builtin_nontemporal_load(reinterpret_cast<const f32x4*>(x) + i);

        // Group = 128 floats = 32 consecutive lanes x float4.
        float a = fabsf(v.x) + fabsf(v.y) + fabsf(v.z) + fabsf(v.w);
#pragma unroll
        for (int m = 1; m <= 16; m <<= 1)
            a += __shfl_xor(a, m, 64);  // masks <32: stays within 32-lane half

        const float mean_c   = fmaxf(a * (1.0f / 128.0f), 1e-5f);
        const float inv_mean = __builtin_amdgcn_rcpf(mean_c);
        const float sidx     = inv_mean * TABSCALE;  // |x| -> table coordinate

        f32x4 o;
#pragma unroll
        for (int e = 0; e < 4; ++e) {
            float xv = v[e];
            float u  = fminf(fabsf(xv) * sidx, (float)TABN - 0.001f);
            float fl = floorf(u);
            float fr = u - fl;
            int idx  = (int)fl;
            float f0 = tab[idx];
            float f1 = tab[idx + 1];
            float r  = fmaf(fr, f1 - f0, f0);   // qx_norm for |x|
            float qn = copysignf(r, xv);        // odd symmetry
            float qx = qn * mean_c;             // un-normalize
            o[e] = fmaf(pressure, qx - xv, xv); // lerp
        }
        __builtin_nontemporal_store(o, reinterpret_cast<f32x4*>(out) + i);
    }
}

extern "C" void kernel_launch(void* const* d_in, const int* in_sizes, int n_in,
                              void* d_out, int out_size, void* d_ws, size_t ws_size,
                              hipStream_t stream)
{
    const float* x  = (const float*)d_in[0];
    const float* cb = (const float*)d_in[1];
    const float* pp = (const float*)d_in[2];  // pressure (1-elem array)
    const float* tp = (const float*)d_in[3];  // temp (1-elem array)
    float* out = (float*)d_out;

    int n4 = in_sizes[0] / 4;   // 4194304 float4s; multiple of 32 => groups align
    dim3 grid(2048), block(256);
    hipLaunchKernelGGL(tq_kernel, grid, block, 0, stream,
                       x, cb, pp, tp, out, n4);
}